// Round 2
// baseline (2910.684 us; speedup 1.0000x reference)
//
#include <hip/hip_runtime.h>

typedef unsigned short u16;
typedef __bf16 bf16x8 __attribute__((ext_vector_type(8)));
typedef float f32x4 __attribute__((ext_vector_type(4)));
typedef u16 u16x8 __attribute__((ext_vector_type(8)));

#define DEVINL __device__ __forceinline__

static constexpr int Tn  = 512;
static constexpr int Dn  = 512;
static constexpr int Hn  = 8;
static constexpr int HSn = 64;
static constexpr int Vn  = 32000;
static constexpr int Lnum = 8;
static constexpr int DFn = 2048;
static constexpr int BTn = 2048;   // B*T

DEVINL u16 f2bf(float f) {
  unsigned u = __float_as_uint(f);
  u += 0x7fffu + ((u >> 16) & 1u);
  return (u16)(u >> 16);
}

// ---- weight transpose + convert: out[z][c][r] = bf16(in[z][r][c]) ----------
__global__ __launch_bounds__(256) void transpose_w(const float* __restrict__ in,
                                                   u16* __restrict__ out,
                                                   int R, int C) {
  __shared__ float tile[32][33];
  long zoff = (long)blockIdx.z * R * C;
  int c0 = blockIdx.x * 32, r0 = blockIdx.y * 32;
  for (int e = threadIdx.x; e < 1024; e += 256) {
    int r = e >> 5, c = e & 31;
    tile[r][c] = in[zoff + (long)(r0 + r) * C + (c0 + c)];
  }
  __syncthreads();
  for (int e = threadIdx.x; e < 1024; e += 256) {
    int c = e >> 5, r = e & 31;
    out[zoff + (long)(c0 + c) * R + (r0 + r)] = f2bf(tile[r][c]);
  }
}

// ---- embedding: x[b,t,:] = tok_emb[idx[b,t],:] + pos_emb[t,:] (f32) --------
__global__ __launch_bounds__(256) void embed_kernel(const int* __restrict__ idx,
                                                    const float* __restrict__ tok,
                                                    const float* __restrict__ pos,
                                                    float* __restrict__ x) {
  int i = blockIdx.x * 256 + threadIdx.x;     // over BT*D/4
  int bt = i >> 7;                            // D/4 = 128
  int d4 = (i & 127) * 4;
  int t = bt & (Tn - 1);
  long tk = (long)idx[bt] * Dn + d4;
  f32x4 a = *(const f32x4*)(tok + tk);
  f32x4 p = *(const f32x4*)(pos + (long)t * Dn + d4);
  a = a + p;
  *(f32x4*)(x + (long)bt * Dn + d4) = a;
}

// ---- LayerNorm: f32 in -> bf16 out. wave per row, D=512 --------------------
__global__ __launch_bounds__(256) void ln_kernel(const float* __restrict__ x,
                                                 const float* __restrict__ g,
                                                 const float* __restrict__ b,
                                                 u16* __restrict__ out) {
  int lane = threadIdx.x & 63, wid = threadIdx.x >> 6;
  long row = (long)blockIdx.x * 4 + wid;
  const float* xr = x + row * Dn;
  f32x4 v0 = *(const f32x4*)(xr + lane * 8);
  f32x4 v1 = *(const f32x4*)(xr + lane * 8 + 4);
  float s = v0[0] + v0[1] + v0[2] + v0[3] + v1[0] + v1[1] + v1[2] + v1[3];
  float s2 = v0[0]*v0[0] + v0[1]*v0[1] + v0[2]*v0[2] + v0[3]*v0[3]
           + v1[0]*v1[0] + v1[1]*v1[1] + v1[2]*v1[2] + v1[3]*v1[3];
#pragma unroll
  for (int o = 32; o; o >>= 1) { s += __shfl_xor(s, o); s2 += __shfl_xor(s2, o); }
  float mu = s * (1.f / Dn);
  float rv = rsqrtf(s2 * (1.f / Dn) - mu * mu + 1e-5f);
  u16x8 o8;
#pragma unroll
  for (int j = 0; j < 8; ++j) {
    int c = lane * 8 + j;
    float xv = (j < 4) ? v0[j] : v1[j - 4];
    o8[j] = f2bf((xv - mu) * rv * g[c] + b[c]);
  }
  *(u16x8*)(out + row * Dn + lane * 8) = o8;
}

// ---- generic bf16 GEMM: C = A(MxK) * Bt(NxK)^T with epilogue ---------------
// A,Bt row-major ld=K. Frag-linear LDS (per-lane permuted global src, linear
// LDS dest via global_load_lds w=16). 4 waves 2x2; 16x16x32 bf16 MFMA.
// C addressing: cOff = (z/zdiv)*zs1 + (z%zdiv)*zs2; element cOff+row*ldc+col.
template<int BM, int BN, bool BIAS, bool RES, bool GELU, bool OBF>
__global__ __launch_bounds__(256, 2)
void gemm_kernel(const u16* __restrict__ A, const u16* __restrict__ B,
                 const float* __restrict__ bias, const float* __restrict__ res,
                 void* __restrict__ Cptr, int M, int N, int K, int ldc,
                 long aBatch, long bBatch, int zdiv, long zs1, long zs2) {
  constexpr int BK = 32;
  constexpr int FM = BM / 32, FN = BN / 32;
  __shared__ __align__(16) u16 lds[2][(BM + BN) * BK];
  const int tid = threadIdx.x, lane = tid & 63, wid = tid >> 6;
  const int z = blockIdx.z;
  const u16* Ab = A + (long)z * aBatch + (long)blockIdx.y * BM * K;
  const u16* Bb = B + (long)z * bBatch + (long)blockIdx.x * BN * K;
  const int wr = wid >> 1, wc = wid & 1;
  const int r16 = lane & 15, kg = lane >> 4;

  f32x4 acc[FM][FN];
#pragma unroll
  for (int i = 0; i < FM; ++i)
#pragma unroll
    for (int j = 0; j < FN; ++j) acc[i][j] = (f32x4){0.f, 0.f, 0.f, 0.f};

  auto stage = [&](int buf, int kt) {
#pragma unroll
    for (int i = 0; i < BM / 64; ++i) {
      int fr = i * 4 + wid;   // fragment row (16 rows each)
      const u16* src = Ab + (long)(fr * 16 + r16) * K + kt * BK + kg * 8;
      u16* dst = &lds[buf][(i * 256 + wid * 64) * 8];
      __builtin_amdgcn_global_load_lds(
          (const __attribute__((address_space(1))) unsigned int*)src,
          (__attribute__((address_space(3))) unsigned int*)dst, 16, 0, 0);
    }
#pragma unroll
    for (int i = 0; i < BN / 64; ++i) {
      int fr = i * 4 + wid;
      const u16* src = Bb + (long)(fr * 16 + r16) * K + kt * BK + kg * 8;
      u16* dst = &lds[buf][BM * BK + (i * 256 + wid * 64) * 8];
      __builtin_amdgcn_global_load_lds(
          (const __attribute__((address_space(1))) unsigned int*)src,
          (__attribute__((address_space(3))) unsigned int*)dst, 16, 0, 0);
    }
  };

  const int NT = K / BK;
  stage(0, 0);
  int cur = 0;
  for (int kt = 0; kt < NT; ++kt) {
    __syncthreads();
    if (kt + 1 < NT) stage(cur ^ 1, kt + 1);
    const u16* la = &lds[cur][0];
    const u16* lb = &lds[cur][BM * BK];
    bf16x8 af[FM], bfr[FN];
#pragma unroll
    for (int mi = 0; mi < FM; ++mi)
      af[mi] = *(const bf16x8*)(la + ((wr * FM + mi) * 64 + lane) * 8);
#pragma unroll
    for (int ni = 0; ni < FN; ++ni)
      bfr[ni] = *(const bf16x8*)(lb + ((wc * FN + ni) * 64 + lane) * 8);
#pragma unroll
    for (int mi = 0; mi < FM; ++mi)
#pragma unroll
      for (int ni = 0; ni < FN; ++ni)
        acc[mi][ni] = __builtin_amdgcn_mfma_f32_16x16x32_bf16(
            af[mi], bfr[ni], acc[mi][ni], 0, 0, 0);
    cur ^= 1;
  }

  long cOff = (long)(z / zdiv) * zs1 + (long)(z % zdiv) * zs2;
#pragma unroll
  for (int mi = 0; mi < FM; ++mi) {
#pragma unroll
    for (int ni = 0; ni < FN; ++ni) {
      int col = blockIdx.x * BN + wc * (BN / 2) + ni * 16 + r16;
      float bv = 0.f;
      if (BIAS) bv = bias[col];
#pragma unroll
      for (int r = 0; r < 4; ++r) {
        int row = blockIdx.y * BM + wr * (BM / 2) + mi * 16 + kg * 4 + r;
        float v = acc[mi][ni][r] + bv;
        if (GELU) v = 0.5f * v * (1.f + erff(v * 0.70710678f));
        long ci = cOff + (long)row * ldc + col;
        if (RES) v += res[ci];
        if (OBF) ((u16*)Cptr)[ci] = f2bf(v);
        else     ((float*)Cptr)[ci] = v;
      }
    }
  }
}

// ---- split qkv f32 (BT x 1536) -> q,k bf16 [bh][t][hs], vT bf16 [bh][hs][t]
__global__ __launch_bounds__(256) void qkv_split(const float* __restrict__ qkv,
                                                 u16* __restrict__ q,
                                                 u16* __restrict__ k,
                                                 u16* __restrict__ vT) {
  __shared__ float vt[32][65];
  int bh = blockIdx.y, b = bh >> 3, h = bh & 7;
  int t0 = blockIdx.x * 32;
  for (int e = threadIdx.x; e < 2048; e += 256) {
    int tt = e >> 6, d = e & 63;
    long src = ((long)(b * Tn + t0 + tt)) * (3 * Dn) + h * HSn + d;
    long dst = ((long)bh * Tn + t0 + tt) * HSn + d;
    q[dst] = f2bf(qkv[src]);
    k[dst] = f2bf(qkv[src + Dn]);
    vt[tt][d] = qkv[src + 2 * Dn];
  }
  __syncthreads();
  for (int e = threadIdx.x; e < 2048; e += 256) {
    int d = e >> 5, tt = e & 31;
    vT[((long)bh * HSn + d) * Tn + t0 + tt] = f2bf(vt[tt][d]);
  }
}

// ---- softmax over S rows (f32) -> P bf16; optional causal mask -------------
__global__ __launch_bounds__(256) void softmax_kernel(const float* __restrict__ S,
                                                      u16* __restrict__ P,
                                                      int causal) {
  int lane = threadIdx.x & 63, wid = threadIdx.x >> 6;
  int t = blockIdx.x * 4 + wid;
  long base = ((long)blockIdx.y * Tn + t) * Tn;
  const float* rp = S + base;
  f32x4 a = *(const f32x4*)(rp + lane * 8);
  f32x4 bq = *(const f32x4*)(rp + lane * 8 + 4);
  float v[8];
  float m = -1e30f;
#pragma unroll
  for (int j = 0; j < 8; ++j) {
    int c = lane * 8 + j;
    float x = ((j < 4) ? a[j] : bq[j - 4]) * 0.125f;   // HS^-0.5 = 1/8
    bool ok = (!causal) || (c <= t);
    v[j] = ok ? x : -1e30f;
    m = fmaxf(m, v[j]);
  }
#pragma unroll
  for (int o = 32; o; o >>= 1) m = fmaxf(m, __shfl_xor(m, o));
  float p[8], sum = 0.f;
#pragma unroll
  for (int j = 0; j < 8; ++j) { p[j] = __expf(v[j] - m); sum += p[j]; }
#pragma unroll
  for (int o = 32; o; o >>= 1) sum += __shfl_xor(sum, o);
  float inv = 1.f / sum;
  u16x8 o8;
#pragma unroll
  for (int j = 0; j < 8; ++j) o8[j] = f2bf(p[j] * inv);
  *(u16x8*)(P + base + lane * 8) = o8;
}

// ---- loss: per-row online logsumexp over V, atomicAdd mean NLL -------------
__global__ __launch_bounds__(256) void loss_kernel(const float* __restrict__ logits,
                                                   const int* __restrict__ targets,
                                                   float* __restrict__ loss) {
  int row = blockIdx.x, tid = threadIdx.x;
  int lane = tid & 63, wid = tid >> 6;
  const float* lr = logits + (long)row * Vn;
  float m = -1e30f, s = 0.f;
  for (int c = tid; c < Vn; c += 256) {
    float x = lr[c];
    float nm = fmaxf(m, x);
    s = s * __expf(m - nm) + __expf(x - nm);
    m = nm;
  }
#pragma unroll
  for (int o = 32; o; o >>= 1) {
    float om = __shfl_xor(m, o), os = __shfl_xor(s, o);
    float nm = fmaxf(m, om);
    s = s * __expf(m - nm) + os * __expf(om - nm);
    m = nm;
  }
  __shared__ float rm[4], rs[4];
  if (lane == 0) { rm[wid] = m; rs[wid] = s; }
  __syncthreads();
  if (tid == 0) {
    float M = rm[0], S = rs[0];
#pragma unroll
    for (int w = 1; w < 4; ++w) {
      float nm = fmaxf(M, rm[w]);
      S = S * __expf(M - nm) + rs[w] * __expf(rm[w] - nm);
      M = nm;
    }
    float lse = M + logf(S);
    float nll = lse - lr[targets[row]];
    atomicAdd(loss, nll * (1.f / BTn));
  }
}

// ============================================================================
extern "C" void kernel_launch(void* const* d_in, const int* in_sizes, int n_in,
                              void* d_out, int out_size, void* d_ws, size_t ws_size,
                              hipStream_t stream) {
  const int*   idx      = (const int*)d_in[0];
  const int*   targets  = (const int*)d_in[1];
  const float* tok_emb  = (const float*)d_in[2];
  const float* pos_emb  = (const float*)d_in[3];
  const float* un_qkv_w = (const float*)d_in[4];
  const float* un_qkv_b = (const float*)d_in[5];
  const float* un_proj_w= (const float*)d_in[6];
  const float* un_proj_b= (const float*)d_in[7];
  const float* m_qkv_w  = (const float*)d_in[8];
  const float* m_qkv_b  = (const float*)d_in[9];
  const float* m_proj_w = (const float*)d_in[10];
  const float* m_proj_b = (const float*)d_in[11];
  const float* ff_w1    = (const float*)d_in[12];
  const float* ff_b1    = (const float*)d_in[13];
  const float* ff_w2    = (const float*)d_in[14];
  const float* ff_b2    = (const float*)d_in[15];
  const float* ln1_g    = (const float*)d_in[16];
  const float* ln1_b    = (const float*)d_in[17];
  const float* ln2_g    = (const float*)d_in[18];
  const float* ln2_b    = (const float*)d_in[19];
  const float* lnf_g    = (const float*)d_in[20];
  const float* lnf_b    = (const float*)d_in[21];
  const float* w_out    = (const float*)d_in[22];
  const float* b_out    = (const float*)d_in[23];

  char* wsp = (char*)d_ws;
  auto alloc = [&](size_t bytes) -> void* {
    void* p = (void*)wsp;
    wsp += (bytes + 255) & ~(size_t)255;
    return p;
  };
  u16* unqkvT = (u16*)alloc((size_t)Lnum * 3 * Dn * Dn * 2);
  u16* mqkvT  = (u16*)alloc((size_t)Lnum * 3 * Dn * Dn * 2);
  u16* unprojT= (u16*)alloc((size_t)Lnum * Dn * Dn * 2);
  u16* mprojT = (u16*)alloc((size_t)Lnum * Dn * Dn * 2);
  u16* ff1T   = (u16*)alloc((size_t)Lnum * Dn * DFn * 2);
  u16* ff2T   = (u16*)alloc((size_t)Lnum * DFn * Dn * 2);
  u16* woutT  = (u16*)alloc((size_t)Dn * Vn * 2);
  float* x    = (float*)alloc((size_t)BTn * Dn * 4);
  float* x2   = (float*)alloc((size_t)BTn * Dn * 4);
  u16* xn     = (u16*)alloc((size_t)BTn * Dn * 2);
  u16* qb     = (u16*)alloc((size_t)32 * Tn * HSn * 2);
  u16* kb     = (u16*)alloc((size_t)32 * Tn * HSn * 2);
  u16* vT     = (u16*)alloc((size_t)32 * HSn * Tn * 2);
  float* Sb   = (float*)alloc((size_t)32 * Tn * Tn * 4);
  u16* Pb     = (u16*)alloc((size_t)32 * Tn * Tn * 2);
  u16* ob     = (u16*)alloc((size_t)BTn * Dn * 2);
  // Temporally-disjoint aliases into Sb's region (saves ~21 MB of ws):
  //   qkvb dead after qkv_split (before Sb is written);
  //   hb live only in FF phase (Sb unused there).
  float* qkvb = Sb;
  u16*   hb   = (u16*)Sb;

  dim3 blk(256);

  // --- weight transposes (f32 -> bf16, (K,N) -> (N,K)) ---
  transpose_w<<<dim3(16, 16, 24), blk, 0, stream>>>(un_qkv_w, unqkvT, Dn, Dn);
  transpose_w<<<dim3(16, 16, 24), blk, 0, stream>>>(m_qkv_w,  mqkvT,  Dn, Dn);
  transpose_w<<<dim3(16, 16, 8),  blk, 0, stream>>>(un_proj_w, unprojT, Dn, Dn);
  transpose_w<<<dim3(16, 16, 8),  blk, 0, stream>>>(m_proj_w,  mprojT,  Dn, Dn);
  transpose_w<<<dim3(64, 16, 8),  blk, 0, stream>>>(ff_w1, ff1T, Dn, DFn);
  transpose_w<<<dim3(16, 64, 8),  blk, 0, stream>>>(ff_w2, ff2T, DFn, Dn);
  transpose_w<<<dim3(1000, 16, 1),blk, 0, stream>>>(w_out, woutT, Dn, Vn);

  embed_kernel<<<dim3(BTn * Dn / 4 / 256), blk, 0, stream>>>(idx, tok_emb, pos_emb, x);

  auto run_mha = [&](const float* xin, float* xout, const u16* qkvT_l,
                     const float* qkvb_l, const u16* projT_l, const float* projb_l,
                     const float* g1, const float* b1, int causal) {
    ln_kernel<<<dim3(BTn / 4), blk, 0, stream>>>(xin, g1, b1, xn);
    // qkv: (BT x 512) @ (512 x 1536)
    gemm_kernel<128, 128, true, false, false, false>
        <<<dim3(12, 16, 1), blk, 0, stream>>>(xn, qkvT_l, qkvb_l, nullptr, qkvb,
            BTn, 3 * Dn, Dn, 3 * Dn, 0, 0, 1, 0, 0);
    qkv_split<<<dim3(Tn / 32, 32), blk, 0, stream>>>(qkvb, qb, kb, vT);
    // scores: per (b,h): (T x 64) @ (64 x T)
    gemm_kernel<128, 128, false, false, false, false>
        <<<dim3(4, 4, 32), blk, 0, stream>>>(qb, kb, nullptr, nullptr, Sb,
            Tn, Tn, HSn, Tn, (long)Tn * HSn, (long)Tn * HSn, 1, (long)Tn * Tn, 0);
    softmax_kernel<<<dim3(Tn / 4, 32), blk, 0, stream>>>(Sb, Pb, causal);
    // PV: per (b,h): (T x T) @ (T x 64) -> o[b][t][h*64+d] bf16
    gemm_kernel<64, 64, false, false, false, true>
        <<<dim3(1, 8, 32), blk, 0, stream>>>(Pb, vT, nullptr, nullptr, ob,
            Tn, HSn, Tn, Dn, (long)Tn * Tn, (long)HSn * Tn, Hn, (long)Tn * Dn, (long)HSn);
    // proj + residual: xout = xin + o @ pw + pb
    gemm_kernel<128, 128, true, true, false, false>
        <<<dim3(4, 16, 1), blk, 0, stream>>>(ob, projT_l, projb_l, xin, xout,
            BTn, Dn, Dn, Dn, 0, 0, 1, 0, 0);
  };

  auto run_ff = [&](const float* xin, float* xout, const u16* w1T_l,
                    const float* b1_l, const u16* w2T_l, const float* b2_l,
                    const float* g2, const float* bb2) {
    ln_kernel<<<dim3(BTn / 4), blk, 0, stream>>>(xin, g2, bb2, xn);
    gemm_kernel<128, 128, true, false, true, true>
        <<<dim3(16, 16, 1), blk, 0, stream>>>(xn, w1T_l, b1_l, nullptr, hb,
            BTn, DFn, Dn, DFn, 0, 0, 1, 0, 0);
    gemm_kernel<128, 128, true, true, false, false>
        <<<dim3(4, 16, 1), blk, 0, stream>>>(hb, w2T_l, b2_l, xin, xout,
            BTn, Dn, DFn, Dn, 0, 0, 1, 0, 0);
  };

  for (int l = 0; l < Lnum; ++l) {
    const u16* uqT = unqkvT + (size_t)l * 3 * Dn * Dn;
    const u16* mqT = mqkvT  + (size_t)l * 3 * Dn * Dn;
    const u16* upT = unprojT+ (size_t)l * Dn * Dn;
    const u16* mpT = mprojT + (size_t)l * Dn * Dn;
    const u16* w1T = ff1T   + (size_t)l * Dn * DFn;
    const u16* w2T = ff2T   + (size_t)l * DFn * Dn;
    const float* g1 = ln1_g + l * Dn, *bb1 = ln1_b + l * Dn;
    const float* g2 = ln2_g + l * Dn, *bb2 = ln2_b + l * Dn;

    run_mha(x, x2, uqT, un_qkv_b + l * 3 * Dn, upT, un_proj_b + l * Dn, g1, bb1, 0);
    run_ff(x2, x, w1T, ff_b1 + l * DFn, w2T, ff_b2 + l * Dn, g2, bb2);
    run_mha(x, x2, mqT, m_qkv_b + l * 3 * Dn, mpT, m_proj_b + l * Dn, g1, bb1, 1);
    run_ff(x2, x, w1T, ff_b1 + l * DFn, w2T, ff_b2 + l * Dn, g2, bb2);
  }

  // final LN + logits + loss
  ln_kernel<<<dim3(BTn / 4), blk, 0, stream>>>(x, lnf_g, lnf_b, xn);
  float* logits = (float*)d_out;
  gemm_kernel<128, 128, true, false, false, false>
      <<<dim3(Vn / 128, 16, 1), blk, 0, stream>>>(xn, woutT, b_out, nullptr, logits,
          BTn, Vn, Dn, Vn, 0, 0, 1, 0, 0);
  float* loss_ptr = logits + (size_t)BTn * Vn;
  hipMemsetAsync((void*)loss_ptr, 0, 4, stream);
  loss_kernel<<<dim3(BTn), blk, 0, stream>>>(logits, targets, loss_ptr);
}

// Round 4
// 2438.456 us; speedup vs baseline: 1.1937x; 1.1937x over previous
//
#include <hip/hip_runtime.h>

typedef unsigned short u16;
typedef __bf16 bf16x8 __attribute__((ext_vector_type(8)));
typedef float f32x4 __attribute__((ext_vector_type(4)));
typedef u16 u16x8 __attribute__((ext_vector_type(8)));

#define DEVINL __device__ __forceinline__

static constexpr int Tn  = 512;
static constexpr int Dn  = 512;
static constexpr int Hn  = 8;
static constexpr int HSn = 64;
static constexpr int Vn  = 32000;
static constexpr int Lnum = 8;
static constexpr int DFn = 2048;
static constexpr int BTn = 2048;   // B*T

DEVINL u16 f2bf(float f) {
  unsigned u = __float_as_uint(f);
  u += 0x7fffu + ((u >> 16) & 1u);
  return (u16)(u >> 16);
}

DEVINL void gl_lds16(const u16* src, u16* dst) {
  __builtin_amdgcn_global_load_lds(
      (const __attribute__((address_space(1))) unsigned int*)src,
      (__attribute__((address_space(3))) unsigned int*)dst, 16, 0, 0);
}

// ---- weight transpose + convert: out[z][c][r] = bf16(in[z][r][c]) ----------
__global__ __launch_bounds__(256) void transpose_w(const float* __restrict__ in,
                                                   u16* __restrict__ out,
                                                   int R, int C) {
  __shared__ float tile[32][33];
  long zoff = (long)blockIdx.z * R * C;
  int c0 = blockIdx.x * 32, r0 = blockIdx.y * 32;
  for (int e = threadIdx.x; e < 1024; e += 256) {
    int r = e >> 5, c = e & 31;
    tile[r][c] = in[zoff + (long)(r0 + r) * C + (c0 + c)];
  }
  __syncthreads();
  for (int e = threadIdx.x; e < 1024; e += 256) {
    int c = e >> 5, r = e & 31;
    out[zoff + (long)(c0 + c) * R + (r0 + r)] = f2bf(tile[r][c]);
  }
}

// ---- embedding -------------------------------------------------------------
__global__ __launch_bounds__(256) void embed_kernel(const int* __restrict__ idx,
                                                    const float* __restrict__ tok,
                                                    const float* __restrict__ pos,
                                                    float* __restrict__ x) {
  int i = blockIdx.x * 256 + threadIdx.x;
  int bt = i >> 7;
  int d4 = (i & 127) * 4;
  int t = bt & (Tn - 1);
  long tk = (long)idx[bt] * Dn + d4;
  f32x4 a = *(const f32x4*)(tok + tk);
  f32x4 p = *(const f32x4*)(pos + (long)t * Dn + d4);
  a = a + p;
  *(f32x4*)(x + (long)bt * Dn + d4) = a;
}

// ---- LayerNorm: f32 in -> bf16 out -----------------------------------------
__global__ __launch_bounds__(256) void ln_kernel(const float* __restrict__ x,
                                                 const float* __restrict__ g,
                                                 const float* __restrict__ b,
                                                 u16* __restrict__ out) {
  int lane = threadIdx.x & 63, wid = threadIdx.x >> 6;
  long row = (long)blockIdx.x * 4 + wid;
  const float* xr = x + row * Dn;
  f32x4 v0 = *(const f32x4*)(xr + lane * 8);
  f32x4 v1 = *(const f32x4*)(xr + lane * 8 + 4);
  float s = v0[0] + v0[1] + v0[2] + v0[3] + v1[0] + v1[1] + v1[2] + v1[3];
  float s2 = v0[0]*v0[0] + v0[1]*v0[1] + v0[2]*v0[2] + v0[3]*v0[3]
           + v1[0]*v1[0] + v1[1]*v1[1] + v1[2]*v1[2] + v1[3]*v1[3];
#pragma unroll
  for (int o = 32; o; o >>= 1) { s += __shfl_xor(s, o); s2 += __shfl_xor(s2, o); }
  float mu = s * (1.f / Dn);
  float rv = rsqrtf(s2 * (1.f / Dn) - mu * mu + 1e-5f);
  u16x8 o8;
#pragma unroll
  for (int j = 0; j < 8; ++j) {
    int c = lane * 8 + j;
    float xv = (j < 4) ? v0[j] : v1[j - 4];
    o8[j] = f2bf((xv - mu) * rv * g[c] + b[c]);
  }
  *(u16x8*)(out + row * Dn + lane * 8) = o8;
}

// ---- generic bf16 GEMM with epilogue ---------------------------------------
template<int BM, int BN, bool BIAS, bool RES, bool GELU, bool OBF, bool LOSSP>
__global__ __launch_bounds__(256, 2)
void gemm_kernel(const u16* __restrict__ A, const u16* __restrict__ B,
                 const float* __restrict__ bias, const float* __restrict__ res,
                 void* __restrict__ Cptr, int M, int N, int K, int ldc,
                 long aBatch, long bBatch, int zdiv, long zs1, long zs2,
                 float* __restrict__ lossP) {
  constexpr int BK = 32;
  constexpr int FM = BM / 32, FN = BN / 32;
  __shared__ __align__(16) u16 lds[2][(BM + BN) * BK];
  const int tid = threadIdx.x, lane = tid & 63, wid = tid >> 6;
  const int z = blockIdx.z;
  const u16* Ab = A + (long)z * aBatch + (long)blockIdx.y * BM * K;
  const u16* Bb = B + (long)z * bBatch + (long)blockIdx.x * BN * K;
  const int wr = wid >> 1, wc = wid & 1;
  const int r16 = lane & 15, kg = lane >> 4;

  f32x4 acc[FM][FN];
#pragma unroll
  for (int i = 0; i < FM; ++i)
#pragma unroll
    for (int j = 0; j < FN; ++j) acc[i][j] = (f32x4){0.f, 0.f, 0.f, 0.f};

  auto stage = [&](int buf, int kt) {
#pragma unroll
    for (int i = 0; i < BM / 64; ++i) {
      int fr = i * 4 + wid;
      const u16* src = Ab + (long)(fr * 16 + r16) * K + kt * BK + kg * 8;
      gl_lds16(src, &lds[buf][(i * 4 + wid) * 512]);
    }
#pragma unroll
    for (int i = 0; i < BN / 64; ++i) {
      int fr = i * 4 + wid;
      const u16* src = Bb + (long)(fr * 16 + r16) * K + kt * BK + kg * 8;
      gl_lds16(src, &lds[buf][BM * BK + (i * 4 + wid) * 512]);
    }
  };

  const int NT = K / BK;
  stage(0, 0);
  int cur = 0;
  for (int kt = 0; kt < NT; ++kt) {
    __syncthreads();
    if (kt + 1 < NT) stage(cur ^ 1, kt + 1);
    const u16* la = &lds[cur][0];
    const u16* lb = &lds[cur][BM * BK];
    bf16x8 af[FM], bfr[FN];
#pragma unroll
    for (int mi = 0; mi < FM; ++mi)
      af[mi] = *(const bf16x8*)(la + ((wr * FM + mi) * 64 + lane) * 8);
#pragma unroll
    for (int ni = 0; ni < FN; ++ni)
      bfr[ni] = *(const bf16x8*)(lb + ((wc * FN + ni) * 64 + lane) * 8);
#pragma unroll
    for (int mi = 0; mi < FM; ++mi)
#pragma unroll
      for (int ni = 0; ni < FN; ++ni)
        acc[mi][ni] = __builtin_amdgcn_mfma_f32_16x16x32_bf16(
            af[mi], bfr[ni], acc[mi][ni], 0, 0, 0);
    cur ^= 1;
  }

  if (LOSSP) {
    // write logits (f32) + per-(row, 64col-group) logsumexp partials
#pragma unroll
    for (int mi = 0; mi < FM; ++mi) {
      float vals[FN][4];
#pragma unroll
      for (int ni = 0; ni < FN; ++ni) {
        int col = blockIdx.x * BN + wc * (BN / 2) + ni * 16 + r16;
        float bv = bias[col];
#pragma unroll
        for (int r = 0; r < 4; ++r) {
          int row = blockIdx.y * BM + wr * (BM / 2) + mi * 16 + kg * 4 + r;
          float v = acc[mi][ni][r] + bv;
          ((float*)Cptr)[(long)row * ldc + col] = v;
          vals[ni][r] = v;
        }
      }
#pragma unroll
      for (int r = 0; r < 4; ++r) {
        float mx = vals[0][r];
#pragma unroll
        for (int ni = 1; ni < FN; ++ni) mx = fmaxf(mx, vals[ni][r]);
#pragma unroll
        for (int off = 1; off < 16; off <<= 1) mx = fmaxf(mx, __shfl_xor(mx, off));
        float s = 0.f;
#pragma unroll
        for (int ni = 0; ni < FN; ++ni) s += __expf(vals[ni][r] - mx);
#pragma unroll
        for (int off = 1; off < 16; off <<= 1) s += __shfl_xor(s, off);
        if (r16 == 0) {
          int row = blockIdx.y * BM + wr * (BM / 2) + mi * 16 + kg * 4 + r;
          int grp = blockIdx.x * (BN / 64) + wc;
          float2* pp = (float2*)lossP;
          pp[(long)row * (Vn / 64) + grp] = make_float2(mx, s);
        }
      }
    }
    return;
  }

  long cOff = (long)(z / zdiv) * zs1 + (long)(z % zdiv) * zs2;
#pragma unroll
  for (int mi = 0; mi < FM; ++mi) {
#pragma unroll
    for (int ni = 0; ni < FN; ++ni) {
      int col = blockIdx.x * BN + wc * (BN / 2) + ni * 16 + r16;
      float bv = 0.f;
      if (BIAS) bv = bias[col];
#pragma unroll
      for (int r = 0; r < 4; ++r) {
        int row = blockIdx.y * BM + wr * (BM / 2) + mi * 16 + kg * 4 + r;
        float v = acc[mi][ni][r] + bv;
        if (GELU) v = 0.5f * v * (1.f + erff(v * 0.70710678f));
        long ci = cOff + (long)row * ldc + col;
        if (RES) v += res[ci];
        if (OBF) ((u16*)Cptr)[ci] = f2bf(v);
        else     ((float*)Cptr)[ci] = v;
      }
    }
  }
}

// ---- split qkv bf16 (BT x 1536) -> q,k [bh][t][hs], vT [bh][hs][t] ---------
__global__ __launch_bounds__(256) void qkv_split(const u16* __restrict__ qkv,
                                                 u16* __restrict__ q,
                                                 u16* __restrict__ k,
                                                 u16* __restrict__ vT) {
  __shared__ u16 vt[32][72];
  int bh = blockIdx.y, b = bh >> 3, h = bh & 7;
  int t0 = blockIdx.x * 32;
  for (int e = threadIdx.x; e < 2048; e += 256) {
    int tt = e >> 6, d = e & 63;
    long src = ((long)(b * Tn + t0 + tt)) * (3 * Dn) + h * HSn + d;
    long dst = ((long)bh * Tn + t0 + tt) * HSn + d;
    q[dst] = qkv[src];
    k[dst] = qkv[src + Dn];
    vt[tt][d] = qkv[src + 2 * Dn];
  }
  __syncthreads();
  for (int e = threadIdx.x; e < 2048; e += 256) {
    int d = e >> 5, tt = e & 31;
    vT[((long)bh * HSn + d) * Tn + t0 + tt] = vt[tt][d];
  }
}

// ---- fused flash attention: per block one (bh, 64-row q-tile) --------------
// Q,K: [bh][t][64] bf16; vT: [bh][64][t] bf16; out scattered to (b,t,D) bf16.
template<int CAUSAL>
__global__ __launch_bounds__(256, 2)
void flash_kernel(const u16* __restrict__ qb, const u16* __restrict__ kb,
                  const u16* __restrict__ vTb, u16* __restrict__ ob) {
  __shared__ __align__(16) u16 Qs[8 * 512];    // 64q x 64k  A-frags
  __shared__ __align__(16) u16 Ks[16 * 512];   // 128kt x 64k B-frags
  __shared__ __align__(16) u16 Vs[16 * 512];   // 64d x 128t  B-frags
  __shared__ __align__(16) u16 Ps[16 * 512];   // 64q x 128t  A-frags (per-wave)
  const int tid = threadIdx.x, lane = tid & 63, w = tid >> 6;
  const int r16 = lane & 15, kg = lane >> 4;
  const int bh = blockIdx.y, qt = blockIdx.x, q0 = qt * 64;
  const long bhT = (long)bh * Tn;

  // stage Q once (wave w stages q rows w*16..w*16+15)
#pragma unroll
  for (int ks = 0; ks < 2; ++ks) {
    const u16* src = qb + (bhT + q0 + w * 16 + r16) * 64 + ks * 32 + kg * 8;
    gl_lds16(src, Qs + (ks * 4 + w) * 512);
  }

  f32x4 acc_o[4];
#pragma unroll
  for (int fd = 0; fd < 4; ++fd) acc_o[fd] = (f32x4){0.f, 0.f, 0.f, 0.f};
  float m[4], l[4];
#pragma unroll
  for (int r = 0; r < 4; ++r) { m[r] = -1e30f; l[r] = 0.f; }

  const int nt = CAUSAL ? (qt >> 1) + 1 : 4;
  for (int it = 0; it < nt; ++it) {
    const int kt0 = it * 128;
    __syncthreads();
    // stage K tile (128 x 64) and V^T tile (64 x 128)
#pragma unroll
    for (int j = 0; j < 4; ++j) {
      int idx = j * 4 + w;                   // = ks*8+fn
      int ks = idx >> 3, fn = idx & 7;
      const u16* src = kb + (bhT + kt0 + fn * 16 + r16) * 64 + ks * 32 + kg * 8;
      gl_lds16(src, Ks + idx * 512);
    }
#pragma unroll
    for (int j = 0; j < 4; ++j) {
      int idx = j * 4 + w;                   // = ks*4+fn
      int ks = idx >> 2, fn = idx & 3;
      const u16* src = vTb + ((long)bh * 64 + fn * 16 + r16) * 512 + kt0 + ks * 32 + kg * 8;
      gl_lds16(src, Vs + idx * 512);
    }
    __syncthreads();

    // S = Q @ K^T (wave w: q rows w*16.., kt 0..127)
    f32x4 sa[8];
#pragma unroll
    for (int fn = 0; fn < 8; ++fn) sa[fn] = (f32x4){0.f, 0.f, 0.f, 0.f};
#pragma unroll
    for (int ks = 0; ks < 2; ++ks) {
      bf16x8 aq = *(const bf16x8*)(Qs + (ks * 4 + w) * 512 + lane * 8);
#pragma unroll
      for (int fn = 0; fn < 8; ++fn)
        sa[fn] = __builtin_amdgcn_mfma_f32_16x16x32_bf16(
            aq, *(const bf16x8*)(Ks + (ks * 8 + fn) * 512 + lane * 8), sa[fn], 0, 0, 0);
    }

    const bool masked = CAUSAL && (it == nt - 1);
    // online softmax per r (q = q0 + w*16 + kg*4 + r); cols kt = fn*16+r16
#pragma unroll
    for (int r = 0; r < 4; ++r) {
      float sv[8];
      float mx = -1e30f;
      int qv = q0 + w * 16 + kg * 4 + r;
#pragma unroll
      for (int fn = 0; fn < 8; ++fn) {
        float vv = sa[fn][r] * 0.125f;
        if (masked) {
          int ktv = kt0 + fn * 16 + r16;
          if (ktv > qv) vv = -1e30f;
        }
        sv[fn] = vv;
        mx = fmaxf(mx, vv);
      }
#pragma unroll
      for (int off = 1; off < 16; off <<= 1) mx = fmaxf(mx, __shfl_xor(mx, off));
      float nm = fmaxf(m[r], mx);
      float sc = __expf(m[r] - nm);
      float rs = 0.f;
#pragma unroll
      for (int fn = 0; fn < 8; ++fn) { float p = __expf(sv[fn] - nm); sv[fn] = p; rs += p; }
#pragma unroll
      for (int off = 1; off < 16; off <<= 1) rs += __shfl_xor(rs, off);
      l[r] = l[r] * sc + rs;
      m[r] = nm;
#pragma unroll
      for (int fd = 0; fd < 4; ++fd) acc_o[fd][r] *= sc;
      // scatter P (bf16) into per-wave A-frag region of Ps
#pragma unroll
      for (int fn = 0; fn < 8; ++fn) {
        int t = fn * 16 + r16;
        int q = kg * 4 + r;
        Ps[w * 2048 + (t >> 5) * 512 + ((t >> 3) & 3) * 128 + q * 8 + (t & 7)] = f2bf(sv[fn]);
      }
    }

    // O += P @ V
#pragma unroll
    for (int ks = 0; ks < 4; ++ks) {
      bf16x8 pa = *(const bf16x8*)(Ps + w * 2048 + ks * 512 + lane * 8);
#pragma unroll
      for (int fd = 0; fd < 4; ++fd)
        acc_o[fd] = __builtin_amdgcn_mfma_f32_16x16x32_bf16(
            pa, *(const bf16x8*)(Vs + (ks * 4 + fd) * 512 + lane * 8), acc_o[fd], 0, 0, 0);
    }
  }

  const int b = bh >> 3, h = bh & 7;
#pragma unroll
  for (int fd = 0; fd < 4; ++fd) {
#pragma unroll
    for (int r = 0; r < 4; ++r) {
      int q = q0 + w * 16 + kg * 4 + r;
      int d = fd * 16 + r16;
      ob[((long)(b * Tn + q)) * Dn + h * 64 + d] = f2bf(acc_o[fd][r] / l[r]);
    }
  }
}

// ---- loss combine: per row merge 500 (m,s) partials, NLL, atomic mean ------
__global__ __launch_bounds__(256) void loss_combine(const float* __restrict__ lossP,
                                                    const float* __restrict__ logits,
                                                    const int* __restrict__ targets,
                                                    float* __restrict__ loss) {
  int w = threadIdx.x >> 6, lane = threadIdx.x & 63;
  int row = blockIdx.x * 4 + w;
  const float2* lp = (const float2*)lossP + (long)row * (Vn / 64);
  float m = -1e30f, s = 0.f;
  for (int e = lane; e < Vn / 64; e += 64) {
    float2 p = lp[e];
    float nm = fmaxf(m, p.x);
    s = s * __expf(m - nm) + p.y * __expf(p.x - nm);
    m = nm;
  }
#pragma unroll
  for (int off = 1; off < 64; off <<= 1) {
    float om = __shfl_xor(m, off), os = __shfl_xor(s, off);
    float nm = fmaxf(m, om);
    s = s * __expf(m - nm) + os * __expf(om - nm);
    m = nm;
  }
  if (lane == 0) {
    float lse = m + logf(s);
    float nll = lse - logits[(long)row * Vn + targets[row]];
    atomicAdd(loss, nll * (1.f / BTn));
  }
}

// ============================================================================
extern "C" void kernel_launch(void* const* d_in, const int* in_sizes, int n_in,
                              void* d_out, int out_size, void* d_ws, size_t ws_size,
                              hipStream_t stream) {
  const int*   idx      = (const int*)d_in[0];
  const int*   targets  = (const int*)d_in[1];
  const float* tok_emb  = (const float*)d_in[2];
  const float* pos_emb  = (const float*)d_in[3];
  const float* un_qkv_w = (const float*)d_in[4];
  const float* un_qkv_b = (const float*)d_in[5];
  const float* un_proj_w= (const float*)d_in[6];
  const float* un_proj_b= (const float*)d_in[7];
  const float* m_qkv_w  = (const float*)d_in[8];
  const float* m_qkv_b  = (const float*)d_in[9];
  const float* m_proj_w = (const float*)d_in[10];
  const float* m_proj_b = (const float*)d_in[11];
  const float* ff_w1    = (const float*)d_in[12];
  const float* ff_b1    = (const float*)d_in[13];
  const float* ff_w2    = (const float*)d_in[14];
  const float* ff_b2    = (const float*)d_in[15];
  const float* ln1_g    = (const float*)d_in[16];
  const float* ln1_b    = (const float*)d_in[17];
  const float* ln2_g    = (const float*)d_in[18];
  const float* ln2_b    = (const float*)d_in[19];
  const float* lnf_g    = (const float*)d_in[20];
  const float* lnf_b    = (const float*)d_in[21];
  const float* w_out    = (const float*)d_in[22];
  const float* b_out    = (const float*)d_in[23];

  char* wsp = (char*)d_ws;
  auto alloc = [&](size_t bytes) -> void* {
    void* p = (void*)wsp;
    wsp += (bytes + 255) & ~(size_t)255;
    return p;
  };
  u16* unqkvT = (u16*)alloc((size_t)Lnum * 3 * Dn * Dn * 2);
  u16* mqkvT  = (u16*)alloc((size_t)Lnum * 3 * Dn * Dn * 2);
  u16* unprojT= (u16*)alloc((size_t)Lnum * Dn * Dn * 2);
  u16* mprojT = (u16*)alloc((size_t)Lnum * Dn * Dn * 2);
  u16* ff1T   = (u16*)alloc((size_t)Lnum * Dn * DFn * 2);
  u16* ff2T   = (u16*)alloc((size_t)Lnum * DFn * Dn * 2);
  u16* woutT  = (u16*)alloc((size_t)Dn * Vn * 2);
  float* x    = (float*)alloc((size_t)BTn * Dn * 4);
  float* x2   = (float*)alloc((size_t)BTn * Dn * 4);
  u16* xn     = (u16*)alloc((size_t)BTn * Dn * 2);
  u16* qb     = (u16*)alloc((size_t)32 * Tn * HSn * 2);
  u16* kb     = (u16*)alloc((size_t)32 * Tn * HSn * 2);
  u16* vT     = (u16*)alloc((size_t)32 * HSn * Tn * 2);
  u16* ob     = (u16*)alloc((size_t)BTn * Dn * 2);
  // scr holds qkvb (BT*3D bf16 = 6.3MB) and hb (BT*DF bf16 = 8.4MB) at
  // disjoint times — sized for the LARGER of the two (was a 2.1MB overrun).
  u16* scr    = (u16*)alloc((size_t)BTn * DFn * 2);
  float* lossP= (float*)alloc((size_t)BTn * (Vn / 64) * 8);
  u16* qkvb = scr;
  u16* hb   = scr;

  dim3 blk(256);

  transpose_w<<<dim3(16, 16, 24), blk, 0, stream>>>(un_qkv_w, unqkvT, Dn, Dn);
  transpose_w<<<dim3(16, 16, 24), blk, 0, stream>>>(m_qkv_w,  mqkvT,  Dn, Dn);
  transpose_w<<<dim3(16, 16, 8),  blk, 0, stream>>>(un_proj_w, unprojT, Dn, Dn);
  transpose_w<<<dim3(16, 16, 8),  blk, 0, stream>>>(m_proj_w,  mprojT,  Dn, Dn);
  transpose_w<<<dim3(64, 16, 8),  blk, 0, stream>>>(ff_w1, ff1T, Dn, DFn);
  transpose_w<<<dim3(16, 64, 8),  blk, 0, stream>>>(ff_w2, ff2T, DFn, Dn);
  transpose_w<<<dim3(1000, 16, 1),blk, 0, stream>>>(w_out, woutT, Dn, Vn);

  embed_kernel<<<dim3(BTn * Dn / 4 / 256), blk, 0, stream>>>(idx, tok_emb, pos_emb, x);

  auto run_mha = [&](const float* xin, float* xout, const u16* qkvT_l,
                     const float* qkvb_l, const u16* projT_l, const float* projb_l,
                     const float* g1, const float* b1, int causal) {
    ln_kernel<<<dim3(BTn / 4), blk, 0, stream>>>(xin, g1, b1, xn);
    gemm_kernel<128, 128, true, false, false, true, false>
        <<<dim3(12, 16, 1), blk, 0, stream>>>(xn, qkvT_l, qkvb_l, nullptr, qkvb,
            BTn, 3 * Dn, Dn, 3 * Dn, 0, 0, 1, 0, 0, nullptr);
    qkv_split<<<dim3(Tn / 32, 32), blk, 0, stream>>>(qkvb, qb, kb, vT);
    if (causal)
      flash_kernel<1><<<dim3(8, 32), blk, 0, stream>>>(qb, kb, vT, ob);
    else
      flash_kernel<0><<<dim3(8, 32), blk, 0, stream>>>(qb, kb, vT, ob);
    gemm_kernel<64, 128, true, true, false, false, false>
        <<<dim3(4, 32, 1), blk, 0, stream>>>(ob, projT_l, projb_l, xin, xout,
            BTn, Dn, Dn, Dn, 0, 0, 1, 0, 0, nullptr);
  };

  auto run_ff = [&](const float* xin, float* xout, const u16* w1T_l,
                    const float* b1_l, const u16* w2T_l, const float* b2_l,
                    const float* g2, const float* bb2) {
    ln_kernel<<<dim3(BTn / 4), blk, 0, stream>>>(xin, g2, bb2, xn);
    gemm_kernel<128, 128, true, false, true, true, false>
        <<<dim3(16, 16, 1), blk, 0, stream>>>(xn, w1T_l, b1_l, nullptr, hb,
            BTn, DFn, Dn, DFn, 0, 0, 1, 0, 0, nullptr);
    gemm_kernel<64, 128, true, true, false, false, false>
        <<<dim3(4, 32, 1), blk, 0, stream>>>(hb, w2T_l, b2_l, xin, xout,
            BTn, Dn, DFn, Dn, 0, 0, 1, 0, 0, nullptr);
  };

  for (int l = 0; l < Lnum; ++l) {
    const u16* uqT = unqkvT + (size_t)l * 3 * Dn * Dn;
    const u16* mqT = mqkvT  + (size_t)l * 3 * Dn * Dn;
    const u16* upT = unprojT+ (size_t)l * Dn * Dn;
    const u16* mpT = mprojT + (size_t)l * Dn * Dn;
    const u16* w1T = ff1T   + (size_t)l * Dn * DFn;
    const u16* w2T = ff2T   + (size_t)l * DFn * Dn;
    const float* g1 = ln1_g + l * Dn, *bb1 = ln1_b + l * Dn;
    const float* g2 = ln2_g + l * Dn, *bb2 = ln2_b + l * Dn;

    run_mha(x, x2, uqT, un_qkv_b + l * 3 * Dn, upT, un_proj_b + l * Dn, g1, bb1, 0);
    run_ff(x2, x, w1T, ff_b1 + l * DFn, w2T, ff_b2 + l * Dn, g2, bb2);
    run_mha(x, x2, mqT, m_qkv_b + l * 3 * Dn, mpT, m_proj_b + l * Dn, g1, bb1, 1);
    run_ff(x2, x, w1T, ff_b1 + l * DFn, w2T, ff_b2 + l * Dn, g2, bb2);
  }

  ln_kernel<<<dim3(BTn / 4), blk, 0, stream>>>(x, lnf_g, lnf_b, xn);
  float* logits = (float*)d_out;
  gemm_kernel<128, 128, true, false, false, false, true>
      <<<dim3(Vn / 128, 16, 1), blk, 0, stream>>>(xn, woutT, b_out, nullptr, logits,
          BTn, Vn, Dn, Vn, 0, 0, 1, 0, 0, lossP);
  float* loss_ptr = logits + (size_t)BTn * Vn;
  hipMemsetAsync((void*)loss_ptr, 0, 4, stream);
  loss_combine<<<dim3(BTn / 4), blk, 0, stream>>>(lossP, logits, targets, loss_ptr);
}

// Round 8
// 2199.050 us; speedup vs baseline: 1.3236x; 1.1089x over previous
//
#include <hip/hip_runtime.h>

typedef unsigned short u16;
typedef __bf16 bf16x8 __attribute__((ext_vector_type(8)));
typedef float f32x4 __attribute__((ext_vector_type(4)));
typedef u16 u16x8 __attribute__((ext_vector_type(8)));

#define DEVINL __device__ __forceinline__

static constexpr int Tn  = 512;
static constexpr int Dn  = 512;
static constexpr int Hn  = 8;
static constexpr int HSn = 64;
static constexpr int Vn  = 32000;
static constexpr int Lnum = 8;
static constexpr int DFn = 2048;
static constexpr int BTn = 2048;   // B*T

DEVINL u16 f2bf(float f) {
  unsigned u = __float_as_uint(f);
  u += 0x7fffu + ((u >> 16) & 1u);
  return (u16)(u >> 16);
}

DEVINL void gl_lds16(const u16* src, u16* dst) {
  __builtin_amdgcn_global_load_lds(
      (const __attribute__((address_space(1))) unsigned int*)src,
      (__attribute__((address_space(3))) unsigned int*)dst, 16, 0, 0);
}

// ---- weight transpose + convert: out[z][c][r] = bf16(in[z][r][c]) ----------
__global__ __launch_bounds__(256) void transpose_w(const float* __restrict__ in,
                                                   u16* __restrict__ out,
                                                   int R, int C) {
  __shared__ float tile[32][33];
  long zoff = (long)blockIdx.z * R * C;
  int c0 = blockIdx.x * 32, r0 = blockIdx.y * 32;
  for (int e = threadIdx.x; e < 1024; e += 256) {
    int r = e >> 5, c = e & 31;
    tile[r][c] = in[zoff + (long)(r0 + r) * C + (c0 + c)];
  }
  __syncthreads();
  for (int e = threadIdx.x; e < 1024; e += 256) {
    int c = e >> 5, r = e & 31;
    out[zoff + (long)(c0 + c) * R + (r0 + r)] = f2bf(tile[r][c]);
  }
}

// ---- embedding -------------------------------------------------------------
__global__ __launch_bounds__(256) void embed_kernel(const int* __restrict__ idx,
                                                    const float* __restrict__ tok,
                                                    const float* __restrict__ pos,
                                                    float* __restrict__ x) {
  int i = blockIdx.x * 256 + threadIdx.x;
  int bt = i >> 7;
  int d4 = (i & 127) * 4;
  int t = bt & (Tn - 1);
  long tk = (long)idx[bt] * Dn + d4;
  f32x4 a = *(const f32x4*)(tok + tk);
  f32x4 p = *(const f32x4*)(pos + (long)t * Dn + d4);
  a = a + p;
  *(f32x4*)(x + (long)bt * Dn + d4) = a;
}

// ---- LayerNorm: f32 in -> bf16 out -----------------------------------------
__global__ __launch_bounds__(256) void ln_kernel(const float* __restrict__ x,
                                                 const float* __restrict__ g,
                                                 const float* __restrict__ b,
                                                 u16* __restrict__ out) {
  int lane = threadIdx.x & 63, wid = threadIdx.x >> 6;
  long row = (long)blockIdx.x * 4 + wid;
  const float* xr = x + row * Dn;
  f32x4 v0 = *(const f32x4*)(xr + lane * 8);
  f32x4 v1 = *(const f32x4*)(xr + lane * 8 + 4);
  float s = v0[0] + v0[1] + v0[2] + v0[3] + v1[0] + v1[1] + v1[2] + v1[3];
  float s2 = v0[0]*v0[0] + v0[1]*v0[1] + v0[2]*v0[2] + v0[3]*v0[3]
           + v1[0]*v1[0] + v1[1]*v1[1] + v1[2]*v1[2] + v1[3]*v1[3];
#pragma unroll
  for (int o = 32; o; o >>= 1) { s += __shfl_xor(s, o); s2 += __shfl_xor(s2, o); }
  float mu = s * (1.f / Dn);
  float rv = rsqrtf(s2 * (1.f / Dn) - mu * mu + 1e-5f);
  u16x8 o8;
#pragma unroll
  for (int j = 0; j < 8; ++j) {
    int c = lane * 8 + j;
    float xv = (j < 4) ? v0[j] : v1[j - 4];
    o8[j] = f2bf((xv - mu) * rv * g[c] + b[c]);
  }
  *(u16x8*)(out + row * Dn + lane * 8) = o8;
}

// ---- generic bf16 GEMM with epilogue ---------------------------------------
// LOSSP: grid is (rowTiles, colTiles) so consecutive blocks reuse one B tile.
// QKV:   epilogue scatters q/k/v by decoding col = cls*512 + h*64 + d.
template<int BM, int BN, int MINW, bool BIAS, bool RES, bool GELU, bool OBF,
         bool LOSSP, bool QKV>
__global__ __launch_bounds__(256, MINW)
void gemm_kernel(const u16* __restrict__ A, const u16* __restrict__ B,
                 const float* __restrict__ bias, const float* __restrict__ res,
                 void* __restrict__ Cptr, int M, int N, int K, int ldc,
                 float* __restrict__ lossP,
                 u16* __restrict__ qp, u16* __restrict__ kp, u16* __restrict__ vp) {
  constexpr int BK = 32;
  constexpr int FM = BM / 32, FN = BN / 32;
  __shared__ __align__(16) u16 lds[2][(BM + BN) * BK];
  const int tid = threadIdx.x, lane = tid & 63, wid = tid >> 6;
  const int bxc = LOSSP ? blockIdx.y : blockIdx.x;   // col tile
  const int byr = LOSSP ? blockIdx.x : blockIdx.y;   // row tile
  const u16* Ab = A + (long)byr * BM * K;
  const u16* Bb = B + (long)bxc * BN * K;
  const int wr = wid >> 1, wc = wid & 1;
  const int r16 = lane & 15, kg = lane >> 4;

  f32x4 acc[FM][FN];
#pragma unroll
  for (int i = 0; i < FM; ++i)
#pragma unroll
    for (int j = 0; j < FN; ++j) acc[i][j] = (f32x4){0.f, 0.f, 0.f, 0.f};

  auto stage = [&](int buf, int kt) {
#pragma unroll
    for (int i = 0; i < BM / 64; ++i) {
      int fr = i * 4 + wid;
      const u16* src = Ab + (long)(fr * 16 + r16) * K + kt * BK + kg * 8;
      gl_lds16(src, &lds[buf][(i * 4 + wid) * 512]);
    }
#pragma unroll
    for (int i = 0; i < BN / 64; ++i) {
      int fr = i * 4 + wid;
      const u16* src = Bb + (long)(fr * 16 + r16) * K + kt * BK + kg * 8;
      gl_lds16(src, &lds[buf][BM * BK + (i * 4 + wid) * 512]);
    }
  };

  const int NT = K / BK;
  stage(0, 0);
  int cur = 0;
  for (int kt = 0; kt < NT; ++kt) {
    __syncthreads();
    if (kt + 1 < NT) stage(cur ^ 1, kt + 1);
    const u16* la = &lds[cur][0];
    const u16* lb = &lds[cur][BM * BK];
    bf16x8 af[FM], bfr[FN];
#pragma unroll
    for (int mi = 0; mi < FM; ++mi)
      af[mi] = *(const bf16x8*)(la + ((wr * FM + mi) * 64 + lane) * 8);
#pragma unroll
    for (int ni = 0; ni < FN; ++ni)
      bfr[ni] = *(const bf16x8*)(lb + ((wc * FN + ni) * 64 + lane) * 8);
#pragma unroll
    for (int mi = 0; mi < FM; ++mi)
#pragma unroll
      for (int ni = 0; ni < FN; ++ni)
        acc[mi][ni] = __builtin_amdgcn_mfma_f32_16x16x32_bf16(
            af[mi], bfr[ni], acc[mi][ni], 0, 0, 0);
    cur ^= 1;
  }

  if (QKV) {
    // scatter q,k -> [bh][t][64]; v -> vtmp [bh][t][64] (transposed later)
#pragma unroll
    for (int mi = 0; mi < FM; ++mi) {
#pragma unroll
      for (int ni = 0; ni < FN; ++ni) {
        int col = bxc * BN + wc * (BN / 2) + ni * 16 + r16;
        float bv = bias[col];
        int cls = col >> 9, h = (col >> 6) & 7, d = col & 63;
#pragma unroll
        for (int r = 0; r < 4; ++r) {
          int row = byr * BM + wr * (BM / 2) + mi * 16 + kg * 4 + r;
          int b = row >> 9, t = row & 511;
          long a = ((long)(b * 8 + h) * Tn + t) * HSn + d;
          u16 ov = f2bf(acc[mi][ni][r] + bv);
          if (cls == 0) qp[a] = ov;
          else if (cls == 1) kp[a] = ov;
          else vp[a] = ov;
        }
      }
    }
    return;
  }

  if (LOSSP) {
#pragma unroll
    for (int mi = 0; mi < FM; ++mi) {
      float vals[FN][4];
#pragma unroll
      for (int ni = 0; ni < FN; ++ni) {
        int col = bxc * BN + wc * (BN / 2) + ni * 16 + r16;
        float bv = bias[col];
#pragma unroll
        for (int r = 0; r < 4; ++r) {
          int row = byr * BM + wr * (BM / 2) + mi * 16 + kg * 4 + r;
          float v = acc[mi][ni][r] + bv;
          ((float*)Cptr)[(long)row * ldc + col] = v;
          vals[ni][r] = v;
        }
      }
#pragma unroll
      for (int r = 0; r < 4; ++r) {
        float mx = vals[0][r];
#pragma unroll
        for (int ni = 1; ni < FN; ++ni) mx = fmaxf(mx, vals[ni][r]);
#pragma unroll
        for (int off = 1; off < 16; off <<= 1) mx = fmaxf(mx, __shfl_xor(mx, off));
        float s = 0.f;
#pragma unroll
        for (int ni = 0; ni < FN; ++ni) s += __expf(vals[ni][r] - mx);
#pragma unroll
        for (int off = 1; off < 16; off <<= 1) s += __shfl_xor(s, off);
        if (r16 == 0) {
          int row = byr * BM + wr * (BM / 2) + mi * 16 + kg * 4 + r;
          int grp = bxc * (BN / 64) + wc;
          ((float2*)lossP)[(long)row * (Vn / 64) + grp] = make_float2(mx, s);
        }
      }
    }
    return;
  }

#pragma unroll
  for (int mi = 0; mi < FM; ++mi) {
#pragma unroll
    for (int ni = 0; ni < FN; ++ni) {
      int col = bxc * BN + wc * (BN / 2) + ni * 16 + r16;
      float bv = 0.f;
      if (BIAS) bv = bias[col];
#pragma unroll
      for (int r = 0; r < 4; ++r) {
        int row = byr * BM + wr * (BM / 2) + mi * 16 + kg * 4 + r;
        float v = acc[mi][ni][r] + bv;
        if (GELU) v = 0.5f * v * (1.f + erff(v * 0.70710678f));
        long ci = (long)row * ldc + col;
        if (RES) v += res[ci];
        if (OBF) ((u16*)Cptr)[ci] = f2bf(v);
        else     ((float*)Cptr)[ci] = v;
      }
    }
  }
}

// ---- v transpose: vtmp [bh][t][64] -> vT [bh][64][t] -----------------------
__global__ __launch_bounds__(256) void vtrans(const u16* __restrict__ vtmp,
                                              u16* __restrict__ vT) {
  __shared__ u16 vt[32][72];
  int bh = blockIdx.y;
  int t0 = blockIdx.x * 32;
  for (int e = threadIdx.x; e < 2048; e += 256) {
    int tt = e >> 6, d = e & 63;
    vt[tt][d] = vtmp[((long)bh * Tn + t0 + tt) * HSn + d];
  }
  __syncthreads();
  for (int e = threadIdx.x; e < 2048; e += 256) {
    int d = e >> 5, tt = e & 31;
    vT[((long)bh * HSn + d) * Tn + t0 + tt] = vt[tt][d];
  }
}

// ---- fused flash attention: per block one (bh, 64-row q-tile) --------------
template<int CAUSAL>
__global__ __launch_bounds__(256, 2)
void flash_kernel(const u16* __restrict__ qb, const u16* __restrict__ kb,
                  const u16* __restrict__ vTb, u16* __restrict__ ob) {
  __shared__ __align__(16) u16 Qs[8 * 512];
  __shared__ __align__(16) u16 Ks[16 * 512];
  __shared__ __align__(16) u16 Vs[16 * 512];
  __shared__ __align__(16) u16 Ps[16 * 512];
  const int tid = threadIdx.x, lane = tid & 63, w = tid >> 6;
  const int r16 = lane & 15, kg = lane >> 4;
  const int bh = blockIdx.y, qt = blockIdx.x, q0 = qt * 64;
  const long bhT = (long)bh * Tn;

#pragma unroll
  for (int ks = 0; ks < 2; ++ks) {
    const u16* src = qb + (bhT + q0 + w * 16 + r16) * 64 + ks * 32 + kg * 8;
    gl_lds16(src, Qs + (ks * 4 + w) * 512);
  }

  f32x4 acc_o[4];
#pragma unroll
  for (int fd = 0; fd < 4; ++fd) acc_o[fd] = (f32x4){0.f, 0.f, 0.f, 0.f};
  float m[4], l[4];
#pragma unroll
  for (int r = 0; r < 4; ++r) { m[r] = -1e30f; l[r] = 0.f; }

  const int nt = CAUSAL ? (qt >> 1) + 1 : 4;
  for (int it = 0; it < nt; ++it) {
    const int kt0 = it * 128;
    __syncthreads();
#pragma unroll
    for (int j = 0; j < 4; ++j) {
      int idx = j * 4 + w;
      int ks = idx >> 3, fn = idx & 7;
      const u16* src = kb + (bhT + kt0 + fn * 16 + r16) * 64 + ks * 32 + kg * 8;
      gl_lds16(src, Ks + idx * 512);
    }
#pragma unroll
    for (int j = 0; j < 4; ++j) {
      int idx = j * 4 + w;
      int ks = idx >> 2, fn = idx & 3;
      const u16* src = vTb + ((long)bh * 64 + fn * 16 + r16) * 512 + kt0 + ks * 32 + kg * 8;
      gl_lds16(src, Vs + idx * 512);
    }
    __syncthreads();

    f32x4 sa[8];
#pragma unroll
    for (int fn = 0; fn < 8; ++fn) sa[fn] = (f32x4){0.f, 0.f, 0.f, 0.f};
#pragma unroll
    for (int ks = 0; ks < 2; ++ks) {
      bf16x8 aq = *(const bf16x8*)(Qs + (ks * 4 + w) * 512 + lane * 8);
#pragma unroll
      for (int fn = 0; fn < 8; ++fn)
        sa[fn] = __builtin_amdgcn_mfma_f32_16x16x32_bf16(
            aq, *(const bf16x8*)(Ks + (ks * 8 + fn) * 512 + lane * 8), sa[fn], 0, 0, 0);
    }

    const bool masked = CAUSAL && (it == nt - 1);
#pragma unroll
    for (int r = 0; r < 4; ++r) {
      float sv[8];
      float mx = -1e30f;
      int qv = q0 + w * 16 + kg * 4 + r;
#pragma unroll
      for (int fn = 0; fn < 8; ++fn) {
        float vv = sa[fn][r] * 0.125f;
        if (masked) {
          int ktv = kt0 + fn * 16 + r16;
          if (ktv > qv) vv = -1e30f;
        }
        sv[fn] = vv;
        mx = fmaxf(mx, vv);
      }
#pragma unroll
      for (int off = 1; off < 16; off <<= 1) mx = fmaxf(mx, __shfl_xor(mx, off));
      float nm = fmaxf(m[r], mx);
      float sc = __expf(m[r] - nm);
      float rs = 0.f;
#pragma unroll
      for (int fn = 0; fn < 8; ++fn) { float p = __expf(sv[fn] - nm); sv[fn] = p; rs += p; }
#pragma unroll
      for (int off = 1; off < 16; off <<= 1) rs += __shfl_xor(rs, off);
      l[r] = l[r] * sc + rs;
      m[r] = nm;
#pragma unroll
      for (int fd = 0; fd < 4; ++fd) acc_o[fd][r] *= sc;
#pragma unroll
      for (int fn = 0; fn < 8; ++fn) {
        int t = fn * 16 + r16;
        int q = kg * 4 + r;
        Ps[w * 2048 + (t >> 5) * 512 + ((t >> 3) & 3) * 128 + q * 8 + (t & 7)] = f2bf(sv[fn]);
      }
    }

#pragma unroll
    for (int ks = 0; ks < 4; ++ks) {
      bf16x8 pa = *(const bf16x8*)(Ps + w * 2048 + ks * 512 + lane * 8);
#pragma unroll
      for (int fd = 0; fd < 4; ++fd)
        acc_o[fd] = __builtin_amdgcn_mfma_f32_16x16x32_bf16(
            pa, *(const bf16x8*)(Vs + (ks * 4 + fd) * 512 + lane * 8), acc_o[fd], 0, 0, 0);
    }
  }

  const int b = bh >> 3, h = bh & 7;
#pragma unroll
  for (int fd = 0; fd < 4; ++fd) {
#pragma unroll
    for (int r = 0; r < 4; ++r) {
      int q = q0 + w * 16 + kg * 4 + r;
      int d = fd * 16 + r16;
      ob[((long)(b * Tn + q)) * Dn + h * 64 + d] = f2bf(acc_o[fd][r] / l[r]);
    }
  }
}

// ---- loss combine ----------------------------------------------------------
__global__ __launch_bounds__(256) void loss_combine(const float* __restrict__ lossP,
                                                    const float* __restrict__ logits,
                                                    const int* __restrict__ targets,
                                                    float* __restrict__ loss) {
  int w = threadIdx.x >> 6, lane = threadIdx.x & 63;
  int row = blockIdx.x * 4 + w;
  const float2* lp = (const float2*)lossP + (long)row * (Vn / 64);
  float m = -1e30f, s = 0.f;
  for (int e = lane; e < Vn / 64; e += 64) {
    float2 p = lp[e];
    float nm = fmaxf(m, p.x);
    s = s * __expf(m - nm) + p.y * __expf(p.x - nm);
    m = nm;
  }
#pragma unroll
  for (int off = 1; off < 64; off <<= 1) {
    float om = __shfl_xor(m, off), os = __shfl_xor(s, off);
    float nm = fmaxf(m, om);
    s = s * __expf(m - nm) + os * __expf(om - nm);
    m = nm;
  }
  if (lane == 0) {
    float lse = m + logf(s);
    float nll = lse - logits[(long)row * Vn + targets[row]];
    atomicAdd(loss, nll * (1.f / BTn));
  }
}

// ============================================================================
extern "C" void kernel_launch(void* const* d_in, const int* in_sizes, int n_in,
                              void* d_out, int out_size, void* d_ws, size_t ws_size,
                              hipStream_t stream) {
  const int*   idx      = (const int*)d_in[0];
  const int*   targets  = (const int*)d_in[1];
  const float* tok_emb  = (const float*)d_in[2];
  const float* pos_emb  = (const float*)d_in[3];
  const float* un_qkv_w = (const float*)d_in[4];
  const float* un_qkv_b = (const float*)d_in[5];
  const float* un_proj_w= (const float*)d_in[6];
  const float* un_proj_b= (const float*)d_in[7];
  const float* m_qkv_w  = (const float*)d_in[8];
  const float* m_qkv_b  = (const float*)d_in[9];
  const float* m_proj_w = (const float*)d_in[10];
  const float* m_proj_b = (const float*)d_in[11];
  const float* ff_w1    = (const float*)d_in[12];
  const float* ff_b1    = (const float*)d_in[13];
  const float* ff_w2    = (const float*)d_in[14];
  const float* ff_b2    = (const float*)d_in[15];
  const float* ln1_g    = (const float*)d_in[16];
  const float* ln1_b    = (const float*)d_in[17];
  const float* ln2_g    = (const float*)d_in[18];
  const float* ln2_b    = (const float*)d_in[19];
  const float* lnf_g    = (const float*)d_in[20];
  const float* lnf_b    = (const float*)d_in[21];
  const float* w_out    = (const float*)d_in[22];
  const float* b_out    = (const float*)d_in[23];

  char* wsp = (char*)d_ws;
  auto alloc = [&](size_t bytes) -> void* {
    void* p = (void*)wsp;
    wsp += (bytes + 255) & ~(size_t)255;
    return p;
  };
  u16* unqkvT = (u16*)alloc((size_t)Lnum * 3 * Dn * Dn * 2);
  u16* mqkvT  = (u16*)alloc((size_t)Lnum * 3 * Dn * Dn * 2);
  u16* unprojT= (u16*)alloc((size_t)Lnum * Dn * Dn * 2);
  u16* mprojT = (u16*)alloc((size_t)Lnum * Dn * Dn * 2);
  u16* ff1T   = (u16*)alloc((size_t)Lnum * Dn * DFn * 2);
  u16* ff2T   = (u16*)alloc((size_t)Lnum * DFn * Dn * 2);
  u16* woutT  = (u16*)alloc((size_t)Dn * Vn * 2);
  float* x    = (float*)alloc((size_t)BTn * Dn * 4);
  float* x2   = (float*)alloc((size_t)BTn * Dn * 4);
  u16* xn     = (u16*)alloc((size_t)BTn * Dn * 2);
  u16* qb     = (u16*)alloc((size_t)32 * Tn * HSn * 2);
  u16* kb     = (u16*)alloc((size_t)32 * Tn * HSn * 2);
  u16* vtmp   = (u16*)alloc((size_t)32 * Tn * HSn * 2);
  u16* vT     = (u16*)alloc((size_t)32 * HSn * Tn * 2);
  u16* ob     = (u16*)alloc((size_t)BTn * Dn * 2);
  u16* hb     = (u16*)alloc((size_t)BTn * DFn * 2);
  float* lossP= (float*)alloc((size_t)BTn * (Vn / 64) * 8);

  dim3 blk(256);

  transpose_w<<<dim3(16, 16, 24), blk, 0, stream>>>(un_qkv_w, unqkvT, Dn, Dn);
  transpose_w<<<dim3(16, 16, 24), blk, 0, stream>>>(m_qkv_w,  mqkvT,  Dn, Dn);
  transpose_w<<<dim3(16, 16, 8),  blk, 0, stream>>>(un_proj_w, unprojT, Dn, Dn);
  transpose_w<<<dim3(16, 16, 8),  blk, 0, stream>>>(m_proj_w,  mprojT,  Dn, Dn);
  transpose_w<<<dim3(64, 16, 8),  blk, 0, stream>>>(ff_w1, ff1T, Dn, DFn);
  transpose_w<<<dim3(16, 64, 8),  blk, 0, stream>>>(ff_w2, ff2T, DFn, Dn);
  transpose_w<<<dim3(1000, 16, 1),blk, 0, stream>>>(w_out, woutT, Dn, Vn);

  embed_kernel<<<dim3(BTn * Dn / 4 / 256), blk, 0, stream>>>(idx, tok_emb, pos_emb, x);

  auto run_mha = [&](const float* xin, float* xout, const u16* qkvT_l,
                     const float* qkvb_l, const u16* projT_l, const float* projb_l,
                     const float* g1, const float* b1, int causal) {
    ln_kernel<<<dim3(BTn / 4), blk, 0, stream>>>(xin, g1, b1, xn);
    // qkv GEMM with fused q/k/v scatter (BT x 1536, K=512)
    gemm_kernel<64, 128, 4, true, false, false, false, false, true>
        <<<dim3(12, 32), blk, 0, stream>>>(xn, qkvT_l, qkvb_l, nullptr, nullptr,
            BTn, 3 * Dn, Dn, 0, nullptr, qb, kb, vtmp);
    vtrans<<<dim3(Tn / 32, 32), blk, 0, stream>>>(vtmp, vT);
    if (causal)
      flash_kernel<1><<<dim3(8, 32), blk, 0, stream>>>(qb, kb, vT, ob);
    else
      flash_kernel<0><<<dim3(8, 32), blk, 0, stream>>>(qb, kb, vT, ob);
    gemm_kernel<64, 64, 4, true, true, false, false, false, false>
        <<<dim3(8, 32), blk, 0, stream>>>(ob, projT_l, projb_l, xin, xout,
            BTn, Dn, Dn, Dn, nullptr, nullptr, nullptr, nullptr);
  };

  auto run_ff = [&](const float* xin, float* xout, const u16* w1T_l,
                    const float* b1_l, const u16* w2T_l, const float* b2_l,
                    const float* g2, const float* bb2) {
    ln_kernel<<<dim3(BTn / 4), blk, 0, stream>>>(xin, g2, bb2, xn);
    gemm_kernel<64, 128, 4, true, false, true, true, false, false>
        <<<dim3(16, 32), blk, 0, stream>>>(xn, w1T_l, b1_l, nullptr, hb,
            BTn, DFn, Dn, DFn, nullptr, nullptr, nullptr, nullptr);
    gemm_kernel<64, 64, 4, true, true, false, false, false, false>
        <<<dim3(8, 32), blk, 0, stream>>>(hb, w2T_l, b2_l, xin, xout,
            BTn, Dn, DFn, Dn, nullptr, nullptr, nullptr, nullptr);
  };

  for (int l = 0; l < Lnum; ++l) {
    const u16* uqT = unqkvT + (size_t)l * 3 * Dn * Dn;
    const u16* mqT = mqkvT  + (size_t)l * 3 * Dn * Dn;
    const u16* upT = unprojT+ (size_t)l * Dn * Dn;
    const u16* mpT = mprojT + (size_t)l * Dn * Dn;
    const u16* w1T = ff1T   + (size_t)l * Dn * DFn;
    const u16* w2T = ff2T   + (size_t)l * DFn * Dn;
    const float* g1 = ln1_g + l * Dn, *bb1 = ln1_b + l * Dn;
    const float* g2 = ln2_g + l * Dn, *bb2 = ln2_b + l * Dn;

    run_mha(x, x2, uqT, un_qkv_b + l * 3 * Dn, upT, un_proj_b + l * Dn, g1, bb1, 0);
    run_ff(x2, x, w1T, ff_b1 + l * DFn, w2T, ff_b2 + l * Dn, g2, bb2);
    run_mha(x, x2, mqT, m_qkv_b + l * 3 * Dn, mpT, m_proj_b + l * Dn, g1, bb1, 1);
    run_ff(x2, x, w1T, ff_b1 + l * DFn, w2T, ff_b2 + l * Dn, g2, bb2);
  }

  ln_kernel<<<dim3(BTn / 4), blk, 0, stream>>>(x, lnf_g, lnf_b, xn);
  float* logits = (float*)d_out;
  // logits GEMM: grid (rowTiles=16, colTiles=250); consecutive blocks share B
  gemm_kernel<128, 128, 3, true, false, false, false, true, false>
      <<<dim3(16, Vn / 128), blk, 0, stream>>>(xn, woutT, b_out, nullptr, logits,
          BTn, Vn, Dn, Vn, lossP, nullptr, nullptr, nullptr);
  float* loss_ptr = logits + (size_t)BTn * Vn;
  hipMemsetAsync((void*)loss_ptr, 0, 4, stream);
  loss_combine<<<dim3(BTn / 4), blk, 0, stream>>>(lossP, logits, targets, loss_ptr);
}